// Round 1
// baseline (7352.899 us; speedup 1.0000x reference)
//
#include <hip/hip_runtime.h>
#include <cstdint>
#include <cstddef>

typedef unsigned short u16;
typedef __attribute__((ext_vector_type(8))) short s16x8;
typedef __attribute__((ext_vector_type(4))) float f32x4;

#define N_B 32
#define N_S 512
#define N_F 10
#define N_D 768
#define N_H 12
#define N_L 12
#define N_FF 3072
#define TOK (N_B*N_S)

__device__ __forceinline__ u16 f2bf(float f){
  union { float f; unsigned u; } x; x.f = f;
  unsigned r = x.u + 0x7fffu + ((x.u >> 16) & 1u);
  return (u16)(r >> 16);
}

__device__ __forceinline__ void gload16(const void* g, void* l){
  typedef const __attribute__((address_space(1))) unsigned GU;
  typedef __attribute__((address_space(3))) unsigned LU;
  __builtin_amdgcn_global_load_lds((GU*)(uintptr_t)g, (LU*)(uintptr_t)l, 16, 0, 0);
}

// ---------------- weight transpose + fp32->bf16 convert ----------------
// src: [L][K][N] fp32, dst: [L][N][K] bf16
__global__ __launch_bounds__(256) void conv_t(const float* __restrict__ src,
                                              u16* __restrict__ dst, int K, int N)
{
  __shared__ float t[32][33];
  const size_t moff = (size_t)blockIdx.z * K * N;
  const float* s = src + moff;
  u16* d = dst + moff;
  const int k0 = blockIdx.x*32, n0 = blockIdx.y*32;
  const int tx = threadIdx.x, ty = threadIdx.y;
  #pragma unroll
  for (int i = 0; i < 32; i += 8)
    t[ty+i][tx] = s[(size_t)(k0+ty+i)*N + n0 + tx];
  __syncthreads();
  #pragma unroll
  for (int i = 0; i < 32; i += 8)
    d[(size_t)(n0+ty+i)*K + k0 + tx] = f2bf(t[tx][ty+i]);
}

// ---------------- embedding + positional encoding ----------------
__global__ __launch_bounds__(256) void embed_kernel(
    const float* __restrict__ x, const float* __restrict__ w,
    const float* __restrict__ bias, const float* __restrict__ pe,
    float* __restrict__ h)
{
  __shared__ float xr[N_F];
  const int row = blockIdx.x;            // b*512 + s
  const int s = row & (N_S-1);
  if (threadIdx.x < N_F) xr[threadIdx.x] = x[row*N_F + threadIdx.x];
  __syncthreads();
  for (int d = threadIdx.x; d < N_D; d += 256){
    float acc = bias[d];
    #pragma unroll
    for (int f = 0; f < N_F; f++) acc += xr[f]*w[f*N_D + d];
    h[(size_t)row*N_D + d] = acc*27.712812921102035f + pe[s*N_D + d];
  }
}

// ---------------- LayerNorm (torch-style: ddof=1, eps added to std) ----------------
__global__ __launch_bounds__(256) void ln_kernel(
    const float* __restrict__ h, const float* __restrict__ ga,
    const float* __restrict__ gb, u16* __restrict__ y)
{
  const int lane = threadIdx.x & 63;
  const int row = blockIdx.x*4 + (threadIdx.x >> 6);
  const float* xr = h + (size_t)row*N_D;
  float v[12];
  float s = 0.f;
  #pragma unroll
  for (int i = 0; i < 12; i++){ v[i] = xr[lane + i*64]; s += v[i]; }
  #pragma unroll
  for (int o = 32; o > 0; o >>= 1) s += __shfl_xor(s, o, 64);
  const float m = s * (1.f/768.f);
  float q = 0.f;
  #pragma unroll
  for (int i = 0; i < 12; i++){ float d = v[i]-m; q += d*d; }
  #pragma unroll
  for (int o = 32; o > 0; o >>= 1) q += __shfl_xor(q, o, 64);
  const float inv = 1.f / (sqrtf(q*(1.f/767.f)) + 1e-6f);
  u16* yr = y + (size_t)row*N_D;
  #pragma unroll
  for (int i = 0; i < 12; i++){
    int c = lane + i*64;
    yr[c] = f2bf(ga[c]*(v[i]-m)*inv + gb[c]);
  }
}

// ---------------- bf16 GEMM, m97-style 128x128 tile, BK=32 ----------------
// A: [M][K] bf16, Bt: [N][K] bf16 (pre-transposed), bias: [N] fp32
// MODE 0: scatter bf16 to (B,H,S,DK)    (Q and K buffers)
// MODE 2: scatter bf16 to (B,H,DK,S)    (V transposed)
// MODE 3: fp32 residual add into out[M][N]
// MODE 4: GELU -> bf16 out[M][N]
template<int MODE>
__global__ __launch_bounds__(256) void gemm_bf16(
    const u16* __restrict__ A, const u16* __restrict__ Bt,
    const float* __restrict__ bias, void* __restrict__ outp,
    int M, int N, int K)
{
  __shared__ __align__(16) u16 As[128*32];
  __shared__ __align__(16) u16 Bs[128*32];
  const int tid = threadIdx.x;
  const int wid = tid >> 6, lane = tid & 63;
  const int bm = blockIdx.x, bn = blockIdx.y;
  const u16* Ag = A  + (size_t)bm*128*K;
  const u16* Bg = Bt + (size_t)bn*128*K;

  const int off0 = wid*2048 + lane*16;          // byte offset in 8KB tile
  const int off1 = off0 + 1024;
  const int r0 = off0 >> 6, c0 = (off0 >> 4) & 3;
  const int r1 = off1 >> 6, c1 = (off1 >> 4) & 3;
  const u16* a0 = Ag + (size_t)r0*K + c0*8;
  const u16* a1 = Ag + (size_t)r1*K + c1*8;
  const u16* b0g = Bg + (size_t)r0*K + c0*8;
  const u16* b1g = Bg + (size_t)r1*K + c1*8;
  u16* lA0 = As + wid*1024;   // wave-uniform LDS dest (bytes: wid*2048)
  u16* lA1 = lA0 + 512;
  u16* lB0 = Bs + wid*1024;
  u16* lB1 = lB0 + 512;

  const int wm = (wid >> 1)*64, wn = (wid & 1)*64;
  const int rsel = lane & 15, kg = (lane >> 4)*8;

  f32x4 acc[4][4];
  const f32x4 z = {0.f, 0.f, 0.f, 0.f};
  #pragma unroll
  for (int i = 0; i < 4; i++)
    #pragma unroll
    for (int j = 0; j < 4; j++) acc[i][j] = z;

  for (int kt = 0; kt < K; kt += 32){
    __syncthreads();
    gload16(a0 + kt, lA0);
    gload16(a1 + kt, lA1);
    gload16(b0g + kt, lB0);
    gload16(b1g + kt, lB1);
    __syncthreads();
    s16x8 af[4], bfr[4];
    #pragma unroll
    for (int i = 0; i < 4; i++)
      af[i] = *(const s16x8*)(As + (wm + i*16 + rsel)*32 + kg);
    #pragma unroll
    for (int j = 0; j < 4; j++)
      bfr[j] = *(const s16x8*)(Bs + (wn + j*16 + rsel)*32 + kg);
    #pragma unroll
    for (int i = 0; i < 4; i++)
      #pragma unroll
      for (int j = 0; j < 4; j++)
        acc[i][j] = __builtin_amdgcn_mfma_f32_16x16x32_bf16(af[i], bfr[j], acc[i][j], 0, 0, 0);
  }

  const int m0 = bm*128 + wm;
  const int n0 = bn*128 + wn;
  #pragma unroll
  for (int i = 0; i < 4; i++){
    #pragma unroll
    for (int j = 0; j < 4; j++){
      const int colg = n0 + j*16 + rsel;
      const float bv = bias[colg];
      #pragma unroll
      for (int r = 0; r < 4; r++){
        const int rowg = m0 + i*16 + (lane >> 4)*4 + r;
        float val = acc[i][j][r] + bv;
        if (MODE == 0){
          const int bb = rowg >> 9, ss = rowg & 511, hh2 = colg >> 6, dk = colg & 63;
          ((u16*)outp)[(((size_t)(bb*N_H + hh2))*N_S + ss)*64 + dk] = f2bf(val);
        } else if (MODE == 2){
          const int bb = rowg >> 9, ss = rowg & 511, hh2 = colg >> 6, dk = colg & 63;
          ((u16*)outp)[(((size_t)(bb*N_H + hh2))*64 + dk)*N_S + ss] = f2bf(val);
        } else if (MODE == 3){
          ((float*)outp)[(size_t)rowg*N + colg] += val;
        } else if (MODE == 4){
          const float u = 0.7978845608028654f*(val + 0.044715f*val*val*val);
          const float e = __expf(2.f*u);
          const float th = 1.f - 2.f/(e + 1.f);    // tanh(u), NaN-safe at +inf
          ((u16*)outp)[(size_t)rowg*N + colg] = f2bf(0.5f*val*(1.f + th));
        }
      }
    }
  }
}

// ---------------- flash attention ----------------
// q,k: (B,H,S,64) bf16; vt: (B,H,64,S) bf16; o: (B,S,768) bf16
__global__ __launch_bounds__(256) void attn_kernel(
    const u16* __restrict__ q, const u16* __restrict__ k,
    const u16* __restrict__ vt, const int* __restrict__ mask,
    u16* __restrict__ o)
{
  __shared__ int mlds[N_S];
  __shared__ __align__(16) u16 plds[4*32*32];
  const int tid = threadIdx.x, wid = tid >> 6, lane = tid & 63;
  const int bh = blockIdx.x;                  // b*12 + h
  const int b = bh / N_H, hh = bh % N_H;
  const int qt = blockIdx.y;
  mlds[tid]       = mask[b*N_S + tid];
  mlds[tid + 256] = mask[b*N_S + tid + 256];
  __syncthreads();

  const int q0 = qt*128 + wid*32;
  const u16* qb = q  + (size_t)bh*N_S*64;
  const u16* kb = k  + (size_t)bh*N_S*64;
  const u16* vb = vt + (size_t)bh*64*N_S;
  const int rsel = lane & 15, kg = (lane >> 4)*8;
  u16* pw = plds + wid*1024;

  s16x8 qa[2][2];
  #pragma unroll
  for (int i = 0; i < 2; i++)
    #pragma unroll
    for (int c = 0; c < 2; c++)
      qa[i][c] = *(const s16x8*)(qb + (size_t)(q0 + i*16 + rsel)*64 + c*32 + kg);

  f32x4 oc[2][4];
  const f32x4 z = {0.f,0.f,0.f,0.f};
  float mrun[2][4], lrun[2][4];
  #pragma unroll
  for (int i = 0; i < 2; i++){
    #pragma unroll
    for (int dj = 0; dj < 4; dj++) oc[i][dj] = z;
    #pragma unroll
    for (int r = 0; r < 4; r++){ mrun[i][r] = -3.0e38f; lrun[i][r] = 0.f; }
  }

  for (int kv = 0; kv < N_S; kv += 32){
    s16x8 kf[2][2];
    #pragma unroll
    for (int j = 0; j < 2; j++)
      #pragma unroll
      for (int c = 0; c < 2; c++)
        kf[j][c] = *(const s16x8*)(kb + (size_t)(kv + j*16 + rsel)*64 + c*32 + kg);
    f32x4 sc[2][2];
    #pragma unroll
    for (int i = 0; i < 2; i++)
      #pragma unroll
      for (int j = 0; j < 2; j++) sc[i][j] = z;
    #pragma unroll
    for (int i = 0; i < 2; i++)
      #pragma unroll
      for (int j = 0; j < 2; j++)
        #pragma unroll
        for (int c = 0; c < 2; c++)
          sc[i][j] = __builtin_amdgcn_mfma_f32_16x16x32_bf16(qa[i][c], kf[j][c], sc[i][j], 0, 0, 0);

    bool mok[2];
    mok[0] = mlds[kv + rsel] > 0;
    mok[1] = mlds[kv + 16 + rsel] > 0;
    #pragma unroll
    for (int i = 0; i < 2; i++)
      #pragma unroll
      for (int j = 0; j < 2; j++)
        #pragma unroll
        for (int r = 0; r < 4; r++)
          sc[i][j][r] = mok[j] ? sc[i][j][r]*0.125f : -1.0e9f;

    float tmx[2][4];
    #pragma unroll
    for (int i = 0; i < 2; i++)
      #pragma unroll
      for (int r = 0; r < 4; r++) tmx[i][r] = fmaxf(sc[i][0][r], sc[i][1][r]);
    #pragma unroll
    for (int off = 1; off < 16; off <<= 1)
      #pragma unroll
      for (int i = 0; i < 2; i++)
        #pragma unroll
        for (int r = 0; r < 4; r++)
          tmx[i][r] = fmaxf(tmx[i][r], __shfl_xor(tmx[i][r], off, 64));

    float alp[2][4], tsum[2][4];
    #pragma unroll
    for (int i = 0; i < 2; i++)
      #pragma unroll
      for (int r = 0; r < 4; r++){
        float nm = fmaxf(mrun[i][r], tmx[i][r]);
        alp[i][r] = __expf(mrun[i][r] - nm);
        mrun[i][r] = nm;
        float p0 = __expf(sc[i][0][r] - nm);
        float p1 = __expf(sc[i][1][r] - nm);
        sc[i][0][r] = p0; sc[i][1][r] = p1;
        tsum[i][r] = p0 + p1;
      }
    #pragma unroll
    for (int off = 1; off < 16; off <<= 1)
      #pragma unroll
      for (int i = 0; i < 2; i++)
        #pragma unroll
        for (int r = 0; r < 4; r++)
          tsum[i][r] += __shfl_xor(tsum[i][r], off, 64);
    #pragma unroll
    for (int i = 0; i < 2; i++)
      #pragma unroll
      for (int r = 0; r < 4; r++)
        lrun[i][r] = lrun[i][r]*alp[i][r] + tsum[i][r];
    #pragma unroll
    for (int i = 0; i < 2; i++)
      #pragma unroll
      for (int dj = 0; dj < 4; dj++)
        #pragma unroll
        for (int r = 0; r < 4; r++)
          oc[i][dj][r] *= alp[i][r];

    // P (C-layout) -> LDS -> A-fragment layout
    #pragma unroll
    for (int i = 0; i < 2; i++)
      #pragma unroll
      for (int j = 0; j < 2; j++)
        #pragma unroll
        for (int r = 0; r < 4; r++)
          pw[(i*16 + (lane >> 4)*4 + r)*32 + j*16 + rsel] = f2bf(sc[i][j][r]);
    s16x8 pa[2];
    #pragma unroll
    for (int i = 0; i < 2; i++)
      pa[i] = *(const s16x8*)(pw + (i*16 + rsel)*32 + kg);
    s16x8 vf[4];
    #pragma unroll
    for (int dj = 0; dj < 4; dj++)
      vf[dj] = *(const s16x8*)(vb + (size_t)(dj*16 + rsel)*N_S + kv + kg);
    #pragma unroll
    for (int i = 0; i < 2; i++)
      #pragma unroll
      for (int dj = 0; dj < 4; dj++)
        oc[i][dj] = __builtin_amdgcn_mfma_f32_16x16x32_bf16(pa[i], vf[dj], oc[i][dj], 0, 0, 0);
  }

  #pragma unroll
  for (int i = 0; i < 2; i++){
    float rinv[4];
    #pragma unroll
    for (int r = 0; r < 4; r++) rinv[r] = 1.f / lrun[i][r];
    #pragma unroll
    for (int dj = 0; dj < 4; dj++)
      #pragma unroll
      for (int r = 0; r < 4; r++){
        const int srow = q0 + i*16 + (lane >> 4)*4 + r;
        const int col = hh*64 + dj*16 + rsel;
        o[((size_t)b*N_S + srow)*N_D + col] = f2bf(oc[i][dj][r]*rinv[r]);
      }
  }
}

// ---------------- launcher ----------------
extern "C" void kernel_launch(void* const* d_in, const int* in_sizes, int n_in,
                              void* d_out, int out_size, void* d_ws, size_t ws_size,
                              hipStream_t stream)
{
  const float* x     = (const float*)d_in[0];
  const int*   mask  = (const int*)  d_in[1];
  const float* w_emb = (const float*)d_in[2];
  const float* b_emb = (const float*)d_in[3];
  const float* pe    = (const float*)d_in[4];
  const float* wq    = (const float*)d_in[5];
  const float* bq    = (const float*)d_in[6];
  const float* wk    = (const float*)d_in[7];
  const float* bk    = (const float*)d_in[8];
  const float* wv    = (const float*)d_in[9];
  const float* bv    = (const float*)d_in[10];
  const float* wo    = (const float*)d_in[11];
  const float* bo    = (const float*)d_in[12];
  const float* w1    = (const float*)d_in[13];
  const float* b1    = (const float*)d_in[14];
  const float* w2    = (const float*)d_in[15];
  const float* b2    = (const float*)d_in[16];
  const float* ln1a  = (const float*)d_in[17];
  const float* ln1b  = (const float*)d_in[18];
  const float* ln2a  = (const float*)d_in[19];
  const float* ln2b  = (const float*)d_in[20];

  char* ws = (char*)d_ws;
  const size_t WMAT = (size_t)N_D*N_D;     // 589824
  const size_t WFF  = (size_t)N_D*N_FF;    // 2359296
  u16* wq_t = (u16*)ws;
  u16* wk_t = wq_t + (size_t)N_L*WMAT;
  u16* wv_t = wk_t + (size_t)N_L*WMAT;
  u16* wo_t = wv_t + (size_t)N_L*WMAT;
  u16* w1_t = wo_t + (size_t)N_L*WMAT;
  u16* w2_t = w1_t + (size_t)N_L*WFF;
  u16* act  = w2_t + (size_t)N_L*WFF;       // [16384][768] bf16: y / o / y2
  u16* big  = act  + (size_t)TOK*N_D;       // 100.7MB region
  u16* qb   = big;                          // (B,H,S,64)
  u16* kb   = qb  + (size_t)TOK*N_D;
  u16* vtb  = kb  + (size_t)TOK*N_D;        // (B,H,64,S)
  u16* gbuf = big;                          // [16384][3072] (overlays dead q/k/vt)
  float* hbuf = (float*)d_out;

  dim3 tb(32, 8);
  conv_t<<<dim3(24,24,12), tb, 0, stream>>>(wq, wq_t, N_D, N_D);
  conv_t<<<dim3(24,24,12), tb, 0, stream>>>(wk, wk_t, N_D, N_D);
  conv_t<<<dim3(24,24,12), tb, 0, stream>>>(wv, wv_t, N_D, N_D);
  conv_t<<<dim3(24,24,12), tb, 0, stream>>>(wo, wo_t, N_D, N_D);
  conv_t<<<dim3(24,96,12), tb, 0, stream>>>(w1, w1_t, N_D, N_FF);
  conv_t<<<dim3(96,24,12), tb, 0, stream>>>(w2, w2_t, N_FF, N_D);

  embed_kernel<<<TOK, 256, 0, stream>>>(x, w_emb, b_emb, pe, hbuf);

  const dim3 g768(TOK/128, N_D/128);    // (128, 6)
  const dim3 g3072(TOK/128, N_FF/128);  // (128, 24)
  for (int l = 0; l < N_L; l++){
    ln_kernel<<<TOK/4, 256, 0, stream>>>(hbuf, ln1a + l*N_D, ln1b + l*N_D, act);
    gemm_bf16<0><<<g768, 256, 0, stream>>>(act, wq_t + l*WMAT, bq + l*N_D, qb,  TOK, N_D, N_D);
    gemm_bf16<0><<<g768, 256, 0, stream>>>(act, wk_t + l*WMAT, bk + l*N_D, kb,  TOK, N_D, N_D);
    gemm_bf16<2><<<g768, 256, 0, stream>>>(act, wv_t + l*WMAT, bv + l*N_D, vtb, TOK, N_D, N_D);
    attn_kernel<<<dim3(N_B*N_H, 4), 256, 0, stream>>>(qb, kb, vtb, mask, act);
    gemm_bf16<3><<<g768, 256, 0, stream>>>(act, wo_t + l*WMAT, bo + l*N_D, hbuf, TOK, N_D, N_D);
    ln_kernel<<<TOK/4, 256, 0, stream>>>(hbuf, ln2a + l*N_D, ln2b + l*N_D, act);
    gemm_bf16<4><<<g3072, 256, 0, stream>>>(act, w1_t + l*WFF, b1 + l*N_FF, gbuf, TOK, N_FF, N_D);
    gemm_bf16<3><<<g768, 256, 0, stream>>>(gbuf, w2_t + l*WFF, b2 + l*N_D, hbuf, TOK, N_D, N_FF);
  }
}

// Round 2
// 6207.071 us; speedup vs baseline: 1.1846x; 1.1846x over previous
//
#include <hip/hip_runtime.h>
#include <cstdint>
#include <cstddef>

typedef unsigned short u16;
typedef __attribute__((ext_vector_type(8))) short s16x8;
typedef __attribute__((ext_vector_type(4))) float f32x4;

#define N_B 32
#define N_S 512
#define N_F 10
#define N_D 768
#define N_H 12
#define N_L 12
#define N_FF 3072
#define TOK (N_B*N_S)

__device__ __forceinline__ u16 f2bf(float f){
  union { float f; unsigned u; } x; x.f = f;
  unsigned r = x.u + 0x7fffu + ((x.u >> 16) & 1u);
  return (u16)(r >> 16);
}

__device__ __forceinline__ void gload16(const void* g, void* l){
  typedef const __attribute__((address_space(1))) unsigned GU;
  typedef __attribute__((address_space(3))) unsigned LU;
  __builtin_amdgcn_global_load_lds((GU*)(uintptr_t)g, (LU*)(uintptr_t)l, 16, 0, 0);
}

#define VMW8  asm volatile("s_waitcnt vmcnt(8)" ::: "memory")
#define VMW4  asm volatile("s_waitcnt vmcnt(4)" ::: "memory")
#define VMW0  asm volatile("s_waitcnt vmcnt(0)" ::: "memory")
#define LGKM0 asm volatile("s_waitcnt lgkmcnt(0)" ::: "memory")
#define CFENCE asm volatile("" ::: "memory")
#define BARF  do { __builtin_amdgcn_s_barrier(); CFENCE; } while(0)
#define SCHED0 __builtin_amdgcn_sched_barrier(0)

// ---------------- weight transpose + fp32->bf16 convert ----------------
// src: [L][K][N] fp32, dst: [L][N][K] bf16
__global__ __launch_bounds__(256) void conv_t(const float* __restrict__ src,
                                              u16* __restrict__ dst, int K, int N)
{
  __shared__ float t[32][33];
  const size_t moff = (size_t)blockIdx.z * K * N;
  const float* s = src + moff;
  u16* d = dst + moff;
  const int k0 = blockIdx.x*32, n0 = blockIdx.y*32;
  const int tx = threadIdx.x, ty = threadIdx.y;
  #pragma unroll
  for (int i = 0; i < 32; i += 8)
    t[ty+i][tx] = s[(size_t)(k0+ty+i)*N + n0 + tx];
  __syncthreads();
  #pragma unroll
  for (int i = 0; i < 32; i += 8)
    d[(size_t)(n0+ty+i)*K + k0 + tx] = f2bf(t[tx][ty+i]);
}

// ---------------- embedding + positional encoding ----------------
__global__ __launch_bounds__(256) void embed_kernel(
    const float* __restrict__ x, const float* __restrict__ w,
    const float* __restrict__ bias, const float* __restrict__ pe,
    float* __restrict__ h)
{
  __shared__ float xr[N_F];
  const int row = blockIdx.x;            // b*512 + s
  const int s = row & (N_S-1);
  if (threadIdx.x < N_F) xr[threadIdx.x] = x[row*N_F + threadIdx.x];
  __syncthreads();
  for (int d = threadIdx.x; d < N_D; d += 256){
    float acc = bias[d];
    #pragma unroll
    for (int f = 0; f < N_F; f++) acc += xr[f]*w[f*N_D + d];
    h[(size_t)row*N_D + d] = acc*27.712812921102035f + pe[s*N_D + d];
  }
}

// ---------------- LayerNorm (torch-style: ddof=1, eps added to std) ----------------
__global__ __launch_bounds__(256) void ln_kernel(
    const float* __restrict__ h, const float* __restrict__ ga,
    const float* __restrict__ gb, u16* __restrict__ y)
{
  const int lane = threadIdx.x & 63;
  const int row = blockIdx.x*4 + (threadIdx.x >> 6);
  const float* xr = h + (size_t)row*N_D;
  float v[12];
  float s = 0.f;
  #pragma unroll
  for (int i = 0; i < 12; i++){ v[i] = xr[lane + i*64]; s += v[i]; }
  #pragma unroll
  for (int o = 32; o > 0; o >>= 1) s += __shfl_xor(s, o, 64);
  const float m = s * (1.f/768.f);
  float q = 0.f;
  #pragma unroll
  for (int i = 0; i < 12; i++){ float d = v[i]-m; q += d*d; }
  #pragma unroll
  for (int o = 32; o > 0; o >>= 1) q += __shfl_xor(q, o, 64);
  const float inv = 1.f / (sqrtf(q*(1.f/767.f)) + 1e-6f);
  u16* yr = y + (size_t)row*N_D;
  #pragma unroll
  for (int i = 0; i < 12; i++){
    int c = lane + i*64;
    yr[c] = f2bf(ga[c]*(v[i]-m)*inv + gb[c]);
  }
}

// ---------------- bf16 GEMM: 128x128 tile, BK=32, 3-slot counted-vmcnt pipeline ----------------
// A: [M][K] bf16, Bt: [N][K] bf16 (pre-transposed), bias: [N] fp32
// MODE 0: scatter bf16 to (B,H,S,DK)    (Q and K buffers)
// MODE 2: scatter bf16 to (B,H,DK,S)    (V transposed)
// MODE 3: fp32 residual add into out[M][N]
// MODE 4: GELU -> bf16 out[M][N]
template<int MODE>
__global__ __launch_bounds__(256, 3) void gemm_bf16(
    const u16* __restrict__ A, const u16* __restrict__ Bt,
    const float* __restrict__ bias, void* __restrict__ outp,
    int M, int N, int K)
{
  // 3 slots x (A 4096 elem + B 4096 elem) = 48 KB
  __shared__ __align__(16) u16 lds[3*8192];
  const int tid = threadIdx.x;
  const int wid = tid >> 6, lane = tid & 63;
  const int bm = blockIdx.x, bn = blockIdx.y;
  const u16* Ag = A  + (size_t)bm*128*K;
  const u16* Bg = Bt + (size_t)bn*128*K;

  // staging: wave w covers rows [w*32, w*32+32); linear LDS dest, swizzled global src
  const int off0 = wid*2048 + lane*16;          // byte offset in 8KB matrix tile
  const int off1 = off0 + 1024;
  const int r0 = off0 >> 6, c0 = (off0 >> 4) & 3;
  const int r1 = off1 >> 6, c1 = (off1 >> 4) & 3;
  const int c0s = c0 ^ ((r0 >> 1) & 3);         // inverse swizzle on source
  const int c1s = c1 ^ ((r1 >> 1) & 3);
  const u16* a0 = Ag + (size_t)r0*K + c0s*8;
  const u16* a1 = Ag + (size_t)r1*K + c1s*8;
  const u16* b0 = Bg + (size_t)r0*K + c0s*8;
  const u16* b1 = Bg + (size_t)r1*K + c1s*8;
  const int ldst0 = wid*1024;                   // element offset within slot
  const int ldst1 = ldst0 + 512;

  const int wm = (wid >> 1)*64, wn = (wid & 1)*64;
  const int rsel = lane & 15, kg = (lane >> 4)*8;

  // swizzled ds_read element offsets (slot-relative), loop-invariant
  int aoff[4], boff[4];
  #pragma unroll
  for (int i = 0; i < 4; i++){
    const int ra = wm + i*16 + rsel;
    aoff[i] = ra*32 + (kg ^ (((ra >> 1) & 3) << 3));
    const int rb = wn + i*16 + rsel;
    boff[i] = 4096 + rb*32 + (kg ^ (((rb >> 1) & 3) << 3));
  }

  f32x4 acc[4][4];
  const f32x4 z = {0.f, 0.f, 0.f, 0.f};
  #pragma unroll
  for (int i = 0; i < 4; i++)
    #pragma unroll
    for (int j = 0; j < 4; j++) acc[i][j] = z;

#define STAGE(S, KT) do { u16* Lp = lds + (S)*8192;       \
    gload16(a0 + (KT), Lp + ldst0);                       \
    gload16(a1 + (KT), Lp + ldst1);                       \
    gload16(b0 + (KT), Lp + 4096 + ldst0);                \
    gload16(b1 + (KT), Lp + 4096 + ldst1); } while(0)

#define FRAGS(S)                                          \
    const u16* Lp = lds + (S)*8192;                       \
    s16x8 af[4], bfr[4];                                  \
    _Pragma("unroll")                                     \
    for (int i = 0; i < 4; i++) af[i]  = *(const s16x8*)(Lp + aoff[i]); \
    _Pragma("unroll")                                     \
    for (int j = 0; j < 4; j++) bfr[j] = *(const s16x8*)(Lp + boff[j]);

#define MFMA16                                            \
    _Pragma("unroll")                                     \
    for (int i = 0; i < 4; i++)                           \
      _Pragma("unroll")                                   \
      for (int j = 0; j < 4; j++)                         \
        acc[i][j] = __builtin_amdgcn_mfma_f32_16x16x32_bf16(af[i], bfr[j], acc[i][j], 0, 0, 0);

  const int nt = K >> 5;           // >= 24 always here
  STAGE(0, 0); STAGE(1, 32); STAGE(2, 64);
  int sl = 0;
  int t = 0;
  for (; t + 3 < nt; ++t){
    VMW8; BARF;                    // barrier 1: tile t landed in slot sl (all waves)
    {
      FRAGS(sl);
      LGKM0;                       // my reads of slot sl fully done
      BARF;                        // barrier 2: everyone's reads done -> slot reusable
      SCHED0;
      STAGE(sl, (t+3)*32);         // issue loads for tile t+3 (no wait)
      SCHED0;
      MFMA16;
    }
    sl = (sl == 2) ? 0 : sl + 1;
  }
  // tail: tiles nt-3, nt-2, nt-1 (no staging, no barrier-2 needed)
  {
    VMW8; BARF;
    { FRAGS(sl); LGKM0; MFMA16; }
    sl = (sl == 2) ? 0 : sl + 1;
    VMW4; BARF;
    { FRAGS(sl); LGKM0; MFMA16; }
    sl = (sl == 2) ? 0 : sl + 1;
    VMW0; BARF;
    { FRAGS(sl); LGKM0; MFMA16; }
  }
#undef STAGE
#undef FRAGS
#undef MFMA16

  const int m0 = bm*128 + wm;
  const int n0 = bn*128 + wn;
  #pragma unroll
  for (int i = 0; i < 4; i++){
    #pragma unroll
    for (int j = 0; j < 4; j++){
      const int colg = n0 + j*16 + rsel;
      const float bv = bias[colg];
      #pragma unroll
      for (int r = 0; r < 4; r++){
        const int rowg = m0 + i*16 + (lane >> 4)*4 + r;
        float val = acc[i][j][r] + bv;
        if (MODE == 0){
          const int bb = rowg >> 9, ss = rowg & 511, hh2 = colg >> 6, dk = colg & 63;
          ((u16*)outp)[(((size_t)(bb*N_H + hh2))*N_S + ss)*64 + dk] = f2bf(val);
        } else if (MODE == 2){
          const int bb = rowg >> 9, ss = rowg & 511, hh2 = colg >> 6, dk = colg & 63;
          ((u16*)outp)[(((size_t)(bb*N_H + hh2))*64 + dk)*N_S + ss] = f2bf(val);
        } else if (MODE == 3){
          ((float*)outp)[(size_t)rowg*N + colg] += val;
        } else if (MODE == 4){
          const float u = 0.7978845608028654f*(val + 0.044715f*val*val*val);
          const float e = __expf(2.f*u);
          const float th = 1.f - 2.f/(e + 1.f);    // tanh(u), NaN-safe at +inf
          ((u16*)outp)[(size_t)rowg*N + colg] = f2bf(0.5f*val*(1.f + th));
        }
      }
    }
  }
}

// ---------------- flash attention ----------------
// q,k: (B,H,S,64) bf16; vt: (B,H,64,S) bf16; o: (B,S,768) bf16
__global__ __launch_bounds__(256) void attn_kernel(
    const u16* __restrict__ q, const u16* __restrict__ k,
    const u16* __restrict__ vt, const int* __restrict__ mask,
    u16* __restrict__ o)
{
  __shared__ int mlds[N_S];
  __shared__ __align__(16) u16 plds[4*32*32];
  const int tid = threadIdx.x, wid = tid >> 6, lane = tid & 63;
  const int bh = blockIdx.x;                  // b*12 + h
  const int b = bh / N_H, hh = bh % N_H;
  const int qt = blockIdx.y;
  mlds[tid]       = mask[b*N_S + tid];
  mlds[tid + 256] = mask[b*N_S + tid + 256];
  __syncthreads();

  const int q0 = qt*128 + wid*32;
  const u16* qb = q  + (size_t)bh*N_S*64;
  const u16* kb = k  + (size_t)bh*N_S*64;
  const u16* vb = vt + (size_t)bh*64*N_S;
  const int rsel = lane & 15, kg = (lane >> 4)*8;
  u16* pw = plds + wid*1024;

  s16x8 qa[2][2];
  #pragma unroll
  for (int i = 0; i < 2; i++)
    #pragma unroll
    for (int c = 0; c < 2; c++)
      qa[i][c] = *(const s16x8*)(qb + (size_t)(q0 + i*16 + rsel)*64 + c*32 + kg);

  f32x4 oc[2][4];
  const f32x4 z = {0.f,0.f,0.f,0.f};
  float mrun[2][4], lrun[2][4];
  #pragma unroll
  for (int i = 0; i < 2; i++){
    #pragma unroll
    for (int dj = 0; dj < 4; dj++) oc[i][dj] = z;
    #pragma unroll
    for (int r = 0; r < 4; r++){ mrun[i][r] = -3.0e38f; lrun[i][r] = 0.f; }
  }

  for (int kv = 0; kv < N_S; kv += 32){
    s16x8 kf[2][2];
    #pragma unroll
    for (int j = 0; j < 2; j++)
      #pragma unroll
      for (int c = 0; c < 2; c++)
        kf[j][c] = *(const s16x8*)(kb + (size_t)(kv + j*16 + rsel)*64 + c*32 + kg);
    f32x4 sc[2][2];
    #pragma unroll
    for (int i = 0; i < 2; i++)
      #pragma unroll
      for (int j = 0; j < 2; j++) sc[i][j] = z;
    __builtin_amdgcn_s_setprio(1);
    #pragma unroll
    for (int i = 0; i < 2; i++)
      #pragma unroll
      for (int j = 0; j < 2; j++)
        #pragma unroll
        for (int c = 0; c < 2; c++)
          sc[i][j] = __builtin_amdgcn_mfma_f32_16x16x32_bf16(qa[i][c], kf[j][c], sc[i][j], 0, 0, 0);
    __builtin_amdgcn_s_setprio(0);

    bool mok[2];
    mok[0] = mlds[kv + rsel] > 0;
    mok[1] = mlds[kv + 16 + rsel] > 0;
    #pragma unroll
    for (int i = 0; i < 2; i++)
      #pragma unroll
      for (int j = 0; j < 2; j++)
        #pragma unroll
        for (int r = 0; r < 4; r++)
          sc[i][j][r] = mok[j] ? sc[i][j][r]*0.125f : -1.0e9f;

    float tmx[2][4];
    #pragma unroll
    for (int i = 0; i < 2; i++)
      #pragma unroll
      for (int r = 0; r < 4; r++) tmx[i][r] = fmaxf(sc[i][0][r], sc[i][1][r]);
    #pragma unroll
    for (int off = 1; off < 16; off <<= 1)
      #pragma unroll
      for (int i = 0; i < 2; i++)
        #pragma unroll
        for (int r = 0; r < 4; r++)
          tmx[i][r] = fmaxf(tmx[i][r], __shfl_xor(tmx[i][r], off, 64));

    float alp[2][4], tsum[2][4];
    #pragma unroll
    for (int i = 0; i < 2; i++)
      #pragma unroll
      for (int r = 0; r < 4; r++){
        float nm = fmaxf(mrun[i][r], tmx[i][r]);
        alp[i][r] = __expf(mrun[i][r] - nm);
        mrun[i][r] = nm;
        float p0 = __expf(sc[i][0][r] - nm);
        float p1 = __expf(sc[i][1][r] - nm);
        sc[i][0][r] = p0; sc[i][1][r] = p1;
        tsum[i][r] = p0 + p1;
      }
    #pragma unroll
    for (int off = 1; off < 16; off <<= 1)
      #pragma unroll
      for (int i = 0; i < 2; i++)
        #pragma unroll
        for (int r = 0; r < 4; r++)
          tsum[i][r] += __shfl_xor(tsum[i][r], off, 64);
    #pragma unroll
    for (int i = 0; i < 2; i++)
      #pragma unroll
      for (int r = 0; r < 4; r++)
        lrun[i][r] = lrun[i][r]*alp[i][r] + tsum[i][r];
    #pragma unroll
    for (int i = 0; i < 2; i++)
      #pragma unroll
      for (int dj = 0; dj < 4; dj++)
        #pragma unroll
        for (int r = 0; r < 4; r++)
          oc[i][dj][r] *= alp[i][r];

    // P (C-layout) -> LDS -> A-fragment layout
    #pragma unroll
    for (int i = 0; i < 2; i++)
      #pragma unroll
      for (int j = 0; j < 2; j++)
        #pragma unroll
        for (int r = 0; r < 4; r++)
          pw[(i*16 + (lane >> 4)*4 + r)*32 + j*16 + rsel] = f2bf(sc[i][j][r]);
    s16x8 pa[2];
    #pragma unroll
    for (int i = 0; i < 2; i++)
      pa[i] = *(const s16x8*)(pw + (i*16 + rsel)*32 + kg);
    s16x8 vf[4];
    #pragma unroll
    for (int dj = 0; dj < 4; dj++)
      vf[dj] = *(const s16x8*)(vb + (size_t)(dj*16 + rsel)*N_S + kv + kg);
    __builtin_amdgcn_s_setprio(1);
    #pragma unroll
    for (int i = 0; i < 2; i++)
      #pragma unroll
      for (int dj = 0; dj < 4; dj++)
        oc[i][dj] = __builtin_amdgcn_mfma_f32_16x16x32_bf16(pa[i], vf[dj], oc[i][dj], 0, 0, 0);
    __builtin_amdgcn_s_setprio(0);
  }

  #pragma unroll
  for (int i = 0; i < 2; i++){
    float rinv[4];
    #pragma unroll
    for (int r = 0; r < 4; r++) rinv[r] = 1.f / lrun[i][r];
    #pragma unroll
    for (int dj = 0; dj < 4; dj++)
      #pragma unroll
      for (int r = 0; r < 4; r++){
        const int srow = q0 + i*16 + (lane >> 4)*4 + r;
        const int col = hh*64 + dj*16 + rsel;
        o[((size_t)b*N_S + srow)*N_D + col] = f2bf(oc[i][dj][r]*rinv[r]);
      }
  }
}

// ---------------- launcher ----------------
extern "C" void kernel_launch(void* const* d_in, const int* in_sizes, int n_in,
                              void* d_out, int out_size, void* d_ws, size_t ws_size,
                              hipStream_t stream)
{
  const float* x     = (const float*)d_in[0];
  const int*   mask  = (const int*)  d_in[1];
  const float* w_emb = (const float*)d_in[2];
  const float* b_emb = (const float*)d_in[3];
  const float* pe    = (const float*)d_in[4];
  const float* wq    = (const float*)d_in[5];
  const float* bq    = (const float*)d_in[6];
  const float* wk    = (const float*)d_in[7];
  const float* bk    = (const float*)d_in[8];
  const float* wv    = (const float*)d_in[9];
  const float* bv    = (const float*)d_in[10];
  const float* wo    = (const float*)d_in[11];
  const float* bo    = (const float*)d_in[12];
  const float* w1    = (const float*)d_in[13];
  const float* b1    = (const float*)d_in[14];
  const float* w2    = (const float*)d_in[15];
  const float* b2    = (const float*)d_in[16];
  const float* ln1a  = (const float*)d_in[17];
  const float* ln1b  = (const float*)d_in[18];
  const float* ln2a  = (const float*)d_in[19];
  const float* ln2b  = (const float*)d_in[20];

  char* ws = (char*)d_ws;
  const size_t WMAT = (size_t)N_D*N_D;     // 589824
  const size_t WFF  = (size_t)N_D*N_FF;    // 2359296
  u16* wq_t = (u16*)ws;
  u16* wk_t = wq_t + (size_t)N_L*WMAT;
  u16* wv_t = wk_t + (size_t)N_L*WMAT;
  u16* wo_t = wv_t + (size_t)N_L*WMAT;
  u16* w1_t = wo_t + (size_t)N_L*WMAT;
  u16* w2_t = w1_t + (size_t)N_L*WFF;
  u16* act  = w2_t + (size_t)N_L*WFF;       // [16384][768] bf16: y / o / y2
  u16* big  = act  + (size_t)TOK*N_D;       // 100.7MB region
  u16* qb   = big;                          // (B,H,S,64)
  u16* kb   = qb  + (size_t)TOK*N_D;
  u16* vtb  = kb  + (size_t)TOK*N_D;        // (B,H,64,S)
  u16* gbuf = big;                          // [16384][3072] (overlays dead q/k/vt)
  float* hbuf = (float*)d_out;

  dim3 tb(32, 8);
  conv_t<<<dim3(24,24,12), tb, 0, stream>>>(wq, wq_t, N_D, N_D);
  conv_t<<<dim3(24,24,12), tb, 0, stream>>>(wk, wk_t, N_D, N_D);
  conv_t<<<dim3(24,24,12), tb, 0, stream>>>(wv, wv_t, N_D, N_D);
  conv_t<<<dim3(24,24,12), tb, 0, stream>>>(wo, wo_t, N_D, N_D);
  conv_t<<<dim3(24,96,12), tb, 0, stream>>>(w1, w1_t, N_D, N_FF);
  conv_t<<<dim3(96,24,12), tb, 0, stream>>>(w2, w2_t, N_FF, N_D);

  embed_kernel<<<TOK, 256, 0, stream>>>(x, w_emb, b_emb, pe, hbuf);

  const dim3 g768(TOK/128, N_D/128);    // (128, 6)
  const dim3 g3072(TOK/128, N_FF/128);  // (128, 24)
  for (int l = 0; l < N_L; l++){
    ln_kernel<<<TOK/4, 256, 0, stream>>>(hbuf, ln1a + l*N_D, ln1b + l*N_D, act);
    gemm_bf16<0><<<g768, 256, 0, stream>>>(act, wq_t + l*WMAT, bq + l*N_D, qb,  TOK, N_D, N_D);
    gemm_bf16<0><<<g768, 256, 0, stream>>>(act, wk_t + l*WMAT, bk + l*N_D, kb,  TOK, N_D, N_D);
    gemm_bf16<2><<<g768, 256, 0, stream>>>(act, wv_t + l*WMAT, bv + l*N_D, vtb, TOK, N_D, N_D);
    attn_kernel<<<dim3(N_B*N_H, 4), 256, 0, stream>>>(qb, kb, vtb, mask, act);
    gemm_bf16<3><<<g768, 256, 0, stream>>>(act, wo_t + l*WMAT, bo + l*N_D, hbuf, TOK, N_D, N_D);
    ln_kernel<<<TOK/4, 256, 0, stream>>>(hbuf, ln2a + l*N_D, ln2b + l*N_D, act);
    gemm_bf16<4><<<g3072, 256, 0, stream>>>(act, w1_t + l*WFF, b1 + l*N_FF, gbuf, TOK, N_FF, N_D);
    gemm_bf16<3><<<g768, 256, 0, stream>>>(gbuf, w2_t + l*WFF, b2 + l*N_D, hbuf, TOK, N_D, N_FF);
  }
}